// Round 1
// baseline (952.428 us; speedup 1.0000x reference)
//
#include <hip/hip_runtime.h>
#include <math.h>

// Problem constants (B,L,E fixed by the reference)
#define Bb 4
#define Ll 2048
#define Ee 512
#define NH 8
#define HD 64

// ---------------------------------------------------------------------------
// QKV projection: out[r,c] = sum_e x[r,e]*W[e,c] + b[c]
// M = B*L = 8192, N = K = 512.  64x64 C-tile, BK=16, 256 threads, 4x4/thread.
// blockIdx.z selects {Q,K,V}.
// ---------------------------------------------------------------------------
__global__ __launch_bounds__(256) void qkv_gemm_kernel(
    const float* __restrict__ x,
    const float* __restrict__ Wq, const float* __restrict__ bq,
    const float* __restrict__ Wk, const float* __restrict__ bk,
    const float* __restrict__ Wv, const float* __restrict__ bv,
    float* __restrict__ Qo, float* __restrict__ Ko, float* __restrict__ Vo)
{
    const float* W; const float* bias; float* out;
    if (blockIdx.z == 0)      { W = Wq; bias = bq; out = Qo; }
    else if (blockIdx.z == 1) { W = Wk; bias = bk; out = Ko; }
    else                      { W = Wv; bias = bv; out = Vo; }

    __shared__ float xs[16][65];   // [kk][m], +1 pad
    __shared__ float ws[16][65];   // [kk][n], +1 pad

    const int t  = threadIdx.x;
    const int tx = t & 15;
    const int ty = t >> 4;
    const int m0 = blockIdx.y * 64;
    const int n0 = blockIdx.x * 64;

    float acc[4][4] = {};

    for (int k0 = 0; k0 < Ee; k0 += 16) {
        __syncthreads();
        #pragma unroll
        for (int it = 0; it < 4; ++it) {
            int lin = it * 256 + t;
            int mm = lin >> 4, kk = lin & 15;          // x tile: 64 rows x 16 k
            xs[kk][mm] = x[(size_t)(m0 + mm) * Ee + (k0 + kk)];
            int kk2 = lin >> 6, c = lin & 63;          // W tile: 16 k x 64 n
            ws[kk2][c] = W[(size_t)(k0 + kk2) * Ee + (n0 + c)];
        }
        __syncthreads();
        #pragma unroll
        for (int kk = 0; kk < 16; ++kk) {
            float a[4], b[4];
            #pragma unroll
            for (int i = 0; i < 4; ++i) a[i] = xs[kk][ty * 4 + i];
            #pragma unroll
            for (int j = 0; j < 4; ++j) b[j] = ws[kk][tx * 4 + j];
            #pragma unroll
            for (int i = 0; i < 4; ++i)
                #pragma unroll
                for (int j = 0; j < 4; ++j)
                    acc[i][j] = fmaf(a[i], b[j], acc[i][j]);
        }
    }

    #pragma unroll
    for (int i = 0; i < 4; ++i) {
        int r = m0 + ty * 4 + i;
        int c = n0 + tx * 4;
        float4 bv4 = *reinterpret_cast<const float4*>(&bias[c]);
        float4 o;
        o.x = acc[i][0] + bv4.x;
        o.y = acc[i][1] + bv4.y;
        o.z = acc[i][2] + bv4.z;
        o.w = acc[i][3] + bv4.w;
        *reinterpret_cast<float4*>(&out[(size_t)r * Ee + c]) = o;
    }
}

// ---------------------------------------------------------------------------
// Flash-style attention, fp32. One block = one (b, h, 64-row q-tile).
// K/V staged in 64-key LDS tiles; S and PV are register-blocked 4x4 GEMMs;
// online softmax with shfl_xor row-reduction across the 16 tx lanes.
// NOTE: reference applies NO 1/sqrt(d) scaling — kept faithful.
// LDS: 65+65+64+65 = 259 cols * 64 rows * 4 B = 66304 B (gfx950 allows 160 KiB).
// ---------------------------------------------------------------------------
__global__ __launch_bounds__(256) void attn_kernel(
    const float* __restrict__ Q, const float* __restrict__ K,
    const float* __restrict__ V, float* __restrict__ out)
{
    __shared__ float qs[64][65];   // [row][d]
    __shared__ float ks[64][65];   // [key][d]  (pad: 16 tx lanes read same d)
    __shared__ float vs[64][64];   // [key][d]  (reads are 2-way = free)
    __shared__ float ps[64][65];   // [key][row] P-transpose staging

    const int t  = threadIdx.x;
    const int tx = t & 15;
    const int ty = t >> 4;
    const int q0 = blockIdx.x * 64;
    const int h  = blockIdx.y;
    const int b  = blockIdx.z;

    const size_t base = ((size_t)b * Ll) * Ee + (size_t)h * HD;

    // stage Q tile once (coalesced: consecutive t -> consecutive d)
    #pragma unroll
    for (int it = 0; it < 16; ++it) {
        int lin = it * 256 + t;
        int r = lin >> 6, d = lin & 63;
        qs[r][d] = Q[base + (size_t)(q0 + r) * Ee + d];
    }

    float acc[4][4] = {};
    float m[4], l[4];
    #pragma unroll
    for (int i = 0; i < 4; ++i) { m[i] = -INFINITY; l[i] = 0.0f; }

    for (int kt = 0; kt < Ll; kt += 64) {
        __syncthreads();   // prev iter's S/PV reads of ks/vs/ps done (also covers qs on iter 0)
        #pragma unroll
        for (int it = 0; it < 16; ++it) {
            int lin = it * 256 + t;
            int r = lin >> 6, d = lin & 63;
            ks[r][d] = K[base + (size_t)(kt + r) * Ee + d];
            vs[r][d] = V[base + (size_t)(kt + r) * Ee + d];
        }
        __syncthreads();

        // S(64x64) = Qtile * Ktile^T, contraction over d
        float s[4][4] = {};
        #pragma unroll 8
        for (int d = 0; d < 64; ++d) {
            float a[4], bb[4];
            #pragma unroll
            for (int i = 0; i < 4; ++i) a[i]  = qs[ty * 4 + i][d];
            #pragma unroll
            for (int j = 0; j < 4; ++j) bb[j] = ks[tx * 4 + j][d];
            #pragma unroll
            for (int i = 0; i < 4; ++i)
                #pragma unroll
                for (int j = 0; j < 4; ++j)
                    s[i][j] = fmaf(a[i], bb[j], s[i][j]);
        }

        // online softmax, per q-row (rows replicated across the 16 tx lanes)
        #pragma unroll
        for (int i = 0; i < 4; ++i) {
            float mx = fmaxf(fmaxf(s[i][0], s[i][1]), fmaxf(s[i][2], s[i][3]));
            #pragma unroll
            for (int off = 1; off <= 8; off <<= 1)
                mx = fmaxf(mx, __shfl_xor(mx, off, 64));
            float mn = fmaxf(m[i], mx);
            float f  = __expf(m[i] - mn);     // m=-inf first tile -> f=0
            l[i] *= f;
            #pragma unroll
            for (int dd = 0; dd < 4; ++dd) acc[i][dd] *= f;
            float su = 0.0f;
            #pragma unroll
            for (int j = 0; j < 4; ++j) { s[i][j] = __expf(s[i][j] - mn); su += s[i][j]; }
            #pragma unroll
            for (int off = 1; off <= 8; off <<= 1)
                su += __shfl_xor(su, off, 64);
            l[i] += su;
            m[i] = mn;
        }

        // P^T -> LDS so the PV contraction dim (keys) becomes the LDS row
        #pragma unroll
        for (int i = 0; i < 4; ++i)
            #pragma unroll
            for (int j = 0; j < 4; ++j)
                ps[tx * 4 + j][ty * 4 + i] = s[i][j];
        __syncthreads();

        // O(64 rows x 64 dims) += P * Vtile, contraction over the 64 keys
        #pragma unroll 8
        for (int j = 0; j < 64; ++j) {
            float a[4], bb[4];
            #pragma unroll
            for (int i = 0; i < 4; ++i)  a[i]  = ps[j][ty * 4 + i];
            #pragma unroll
            for (int dd = 0; dd < 4; ++dd) bb[dd] = vs[j][tx * 4 + dd];
            #pragma unroll
            for (int i = 0; i < 4; ++i)
                #pragma unroll
                for (int dd = 0; dd < 4; ++dd)
                    acc[i][dd] = fmaf(a[i], bb[dd], acc[i][dd]);
        }
    }

    // epilogue: normalize by l and store (float4, coalesced within 16-lane groups)
    #pragma unroll
    for (int i = 0; i < 4; ++i) {
        float inv = 1.0f / l[i];
        int r = q0 + ty * 4 + i;
        float4 o;
        o.x = acc[i][0] * inv;
        o.y = acc[i][1] * inv;
        o.z = acc[i][2] * inv;
        o.w = acc[i][3] * inv;
        *reinterpret_cast<float4*>(&out[base + (size_t)r * Ee + tx * 4]) = o;
    }
}

extern "C" void kernel_launch(void* const* d_in, const int* in_sizes, int n_in,
                              void* d_out, int out_size, void* d_ws, size_t ws_size,
                              hipStream_t stream) {
    const float* x  = (const float*)d_in[0];
    const float* Wq = (const float*)d_in[1];
    const float* bq = (const float*)d_in[2];
    const float* Wk = (const float*)d_in[3];
    const float* bk = (const float*)d_in[4];
    const float* Wv = (const float*)d_in[5];
    const float* bv = (const float*)d_in[6];
    float* outp = (float*)d_out;

    // Workspace layout: Q | K | V, each B*L*E fp32 (16.78 MB each, 50.3 MB total)
    const size_t elems = (size_t)Bb * Ll * Ee;
    float* Qw = (float*)d_ws;
    float* Kw = Qw + elems;
    float* Vw = Kw + elems;

    dim3 gemm_grid(Ee / 64, (Bb * Ll) / 64, 3);   // (8, 128, 3)
    qkv_gemm_kernel<<<gemm_grid, 256, 0, stream>>>(x, Wq, bq, Wk, bk, Wv, bv,
                                                   Qw, Kw, Vw);

    dim3 attn_grid(Ll / 64, NH, Bb);              // (32, 8, 4)
    attn_kernel<<<attn_grid, 256, 0, stream>>>(Qw, Kw, Vw, outp);
}

// Round 9
// 516.523 us; speedup vs baseline: 1.8439x; 1.8439x over previous
//
#include <hip/hip_runtime.h>
#include <math.h>

// Problem constants
#define Bb 4
#define Ll 2048
#define Ee 512
#define NH 8
#define HD 64

typedef __attribute__((ext_vector_type(8))) short bf16x8;   // 8 bf16 = 4 VGPR
typedef __attribute__((ext_vector_type(4))) short bf16x4;   // 8 bytes
typedef __attribute__((ext_vector_type(4))) float f32x4;

#define MFMA16(a, b, c) __builtin_amdgcn_mfma_f32_16x16x32_bf16(a, b, c, 0, 0, 0)

// Split fp32 into bf16 hi + bf16 lo (RNE both). x ≈ hi + lo with ~2^-17 rel err.
__device__ inline void split_bf16(float x, short& hi, short& lo) {
    unsigned u = __float_as_uint(x);
    unsigned r = (u + 0x7fffu + ((u >> 16) & 1u)) & 0xffff0000u;
    hi = (short)(r >> 16);
    float rem = x - __uint_as_float(r);
    unsigned u2 = __float_as_uint(rem);
    unsigned r2 = u2 + 0x7fffu + ((u2 >> 16) & 1u);
    lo = (short)(r2 >> 16);
}

// ---------------------------------------------------------------------------
// QKV projection (fp32 vector GEMM, unchanged math) with hi/lo bf16 epilogue:
//  z=0 Q: [b][h][l][d] linear
//  z=1 K: [b][h][l][d], d pre-swizzled in 8-elem chunks: chunk' = chunk ^ (l&7)
//  z=2 V: transposed [b][h][d][l], l pre-swizzled per 64-group: ch' = ch ^ (d&7)
// n0 = blockIdx.x*64 spans exactly one head (E=512, HD=64) -> h = blockIdx.x.
// ---------------------------------------------------------------------------
__global__ __launch_bounds__(256) void qkv_gemm_kernel(
    const float* __restrict__ x,
    const float* __restrict__ Wq, const float* __restrict__ bq,
    const float* __restrict__ Wk, const float* __restrict__ bk,
    const float* __restrict__ Wv, const float* __restrict__ bv,
    short* __restrict__ Qhi, short* __restrict__ Qlo,
    short* __restrict__ Khi, short* __restrict__ Klo,
    short* __restrict__ Vthi, short* __restrict__ Vtlo)
{
    const float* W; const float* bias;
    if (blockIdx.z == 0)      { W = Wq; bias = bq; }
    else if (blockIdx.z == 1) { W = Wk; bias = bk; }
    else                      { W = Wv; bias = bv; }

    __shared__ float xs[16][65];
    __shared__ float ws[16][65];
    __shared__ float tr[64][65];   // V-transpose staging (z==2 only)

    const int t  = threadIdx.x;
    const int tx = t & 15;
    const int ty = t >> 4;
    const int m0 = blockIdx.y * 64;
    const int n0 = blockIdx.x * 64;
    const int h  = blockIdx.x;

    float acc[4][4] = {};

    for (int k0 = 0; k0 < Ee; k0 += 16) {
        __syncthreads();
        #pragma unroll
        for (int it = 0; it < 4; ++it) {
            int lin = it * 256 + t;
            int mm = lin >> 4, kk = lin & 15;
            xs[kk][mm] = x[(size_t)(m0 + mm) * Ee + (k0 + kk)];
            int kk2 = lin >> 6, c = lin & 63;
            ws[kk2][c] = W[(size_t)(k0 + kk2) * Ee + (n0 + c)];
        }
        __syncthreads();
        #pragma unroll
        for (int kk = 0; kk < 16; ++kk) {
            float a[4], b[4];
            #pragma unroll
            for (int i = 0; i < 4; ++i) a[i] = xs[kk][ty * 4 + i];
            #pragma unroll
            for (int j = 0; j < 4; ++j) b[j] = ws[kk][tx * 4 + j];
            #pragma unroll
            for (int i = 0; i < 4; ++i)
                #pragma unroll
                for (int j = 0; j < 4; ++j)
                    acc[i][j] = fmaf(a[i], b[j], acc[i][j]);
        }
    }

    const float4 bv4 = *reinterpret_cast<const float4*>(&bias[n0 + tx * 4]);
    const int z = blockIdx.z;
    const int b = m0 >> 11;        // 2048 rows per batch
    const int l0 = m0 & 2047;

    if (z < 2) {
        #pragma unroll
        for (int i = 0; i < 4; ++i) {
            int l = l0 + ty * 4 + i;
            size_t rowbase = ((size_t)(b * NH + h) * Ll + l) * (size_t)HD;
            float f[4];
            f[0] = acc[i][0] + bv4.x;
            f[1] = acc[i][1] + bv4.y;
            f[2] = acc[i][2] + bv4.z;
            f[3] = acc[i][3] + bv4.w;
            bf16x4 hv, lv;
            #pragma unroll
            for (int j = 0; j < 4; ++j) {
                short th, tl;                 // scalar temps: vector elements
                split_bf16(f[j], th, tl);     // can't bind to short&
                hv[j] = th;
                lv[j] = tl;
            }
            if (z == 0) {
                *(bf16x4*)(Qhi + rowbase + tx * 4) = hv;
                *(bf16x4*)(Qlo + rowbase + tx * 4) = lv;
            } else {
                int dpos = (((tx >> 1) ^ (l & 7)) << 3) + ((tx & 1) << 2);
                *(bf16x4*)(Khi + rowbase + dpos) = hv;
                *(bf16x4*)(Klo + rowbase + dpos) = lv;
            }
        }
    } else {
        #pragma unroll
        for (int i = 0; i < 4; ++i) {
            tr[ty * 4 + i][tx * 4 + 0] = acc[i][0] + bv4.x;
            tr[ty * 4 + i][tx * 4 + 1] = acc[i][1] + bv4.y;
            tr[ty * 4 + i][tx * 4 + 2] = acc[i][2] + bv4.z;
            tr[ty * 4 + i][tx * 4 + 3] = acc[i][3] + bv4.w;
        }
        __syncthreads();
        #pragma unroll
        for (int it = 0; it < 16; ++it) {
            int lin = it * 256 + t;
            int d = lin >> 6, lloc = lin & 63;
            float f = tr[lloc][d];
            short hi, lo2;
            split_bf16(f, hi, lo2);
            int colp = ((((lloc >> 3) ^ (d & 7)) << 3) | (lloc & 7));
            size_t idx = ((size_t)(b * NH + h) * HD + d) * (size_t)Ll + l0 + colp;
            Vthi[idx] = hi;
            Vtlo[idx] = lo2;
        }
    }
}

// ---------------------------------------------------------------------------
// Flash attention, split-bf16 MFMA (3-product compensation ~ fp32 accuracy).
// 4 waves/block; wave w owns q rows [q0+16w, q0+16w+16). KVBLK=64.
// MFMA 16x16x32 layouts: A row=lane&15, k=(lane>>4)*8+i; B col=lane&15, same k;
// D col=lane&15, row=(lane>>4)*4+reg.
// K/Vt tiles in LDS, XOR-chunk swizzled (pre-swizzled in global by qkv epi).
// P transposed through per-wave swizzled LDS as bf16 hi/lo.
// LDS: 4*8KB (K/V hi/lo) + 2*8KB (P hi/lo) = 48 KB -> 3 blocks/CU.
// ---------------------------------------------------------------------------
__global__ __launch_bounds__(256) void attn_kernel(
    const short* __restrict__ Qhi, const short* __restrict__ Qlo,
    const short* __restrict__ Khi, const short* __restrict__ Klo,
    const short* __restrict__ Vthi, const short* __restrict__ Vtlo,
    float* __restrict__ out)
{
    __shared__ short ksh[4096], ksl[4096], vsh[4096], vsl[4096];
    __shared__ short psh[4][1024], psl[4][1024];

    const int t    = threadIdx.x;
    const int ln   = t & 63;
    const int w    = t >> 6;
    const int lo16 = ln & 15;
    const int hi4  = ln >> 4;
    const int q0   = blockIdx.x * 64;
    const int h    = blockIdx.y;
    const int b    = blockIdx.z;
    const int bh   = b * NH + h;

    // Q A-fragments (held in registers for the whole K-loop)
    const size_t qbase = ((size_t)bh * Ll + q0 + w * 16 + lo16) * (size_t)HD;
    bf16x8 qh[2], ql[2];
    qh[0] = *(const bf16x8*)(Qhi + qbase + hi4 * 8);
    qh[1] = *(const bf16x8*)(Qhi + qbase + 32 + hi4 * 8);
    ql[0] = *(const bf16x8*)(Qlo + qbase + hi4 * 8);
    ql[1] = *(const bf16x8*)(Qlo + qbase + 32 + hi4 * 8);

    f32x4 o[4];
    float m[4], lsum[4];
    #pragma unroll
    for (int i = 0; i < 4; ++i) {
        o[i] = (f32x4){0.f, 0.f, 0.f, 0.f};
        m[i] = -INFINITY;
        lsum[i] = 0.f;
    }

    for (int kt = 0; kt < Ll; kt += 64) {
        __syncthreads();   // previous tile's LDS reads done
        // stage: wave 0->Khi, 1->Klo, 2->Vthi, 3->Vtlo (each 64x64 bf16 = 8KB)
        if (w < 2) {
            const short* src = (w == 0 ? Khi : Klo) + ((size_t)bh * Ll + kt) * (size_t)HD;
            short* dst = (w == 0 ? ksh : ksl);
            #pragma unroll
            for (int it = 0; it < 8; ++it)
                *(bf16x8*)(dst + it * 512 + ln * 8) = *(const bf16x8*)(src + it * 512 + ln * 8);
        } else {
            const short* src0 = (w == 2 ? Vthi : Vtlo) + (size_t)bh * HD * Ll + kt;
            short* dst = (w == 2 ? vsh : vsl);
            #pragma unroll
            for (int it = 0; it < 8; ++it) {
                int row = it * 8 + (ln >> 3);
                *(bf16x8*)(dst + row * 64 + (ln & 7) * 8) =
                    *(const bf16x8*)(src0 + (size_t)row * Ll + (ln & 7) * 8);
            }
        }
        __syncthreads();

        // S = Q K^T : per wave 16(q) x 64(key), 3-way split accumulation
        f32x4 s[4];
        #pragma unroll
        for (int ct = 0; ct < 4; ++ct) {
            s[ct] = (f32x4){0.f, 0.f, 0.f, 0.f};
            #pragma unroll
            for (int kc = 0; kc < 2; ++kc) {
                int key = ct * 16 + lo16;
                int c   = kc * 4 + hi4;
                int idx = key * 64 + ((c ^ (key & 7)) << 3);
                bf16x8 kbh = *(const bf16x8*)(ksh + idx);
                bf16x8 kbl = *(const bf16x8*)(ksl + idx);
                s[ct] = MFMA16(qh[kc], kbh, s[ct]);
                s[ct] = MFMA16(qh[kc], kbl, s[ct]);
                s[ct] = MFMA16(ql[kc], kbh, s[ct]);
            }
        }

        // online softmax per q-row (lane's rows: hi4*4 + r, replicated over 16 lanes)
        #pragma unroll
        for (int r = 0; r < 4; ++r) {
            float mx = fmaxf(fmaxf(s[0][r], s[1][r]), fmaxf(s[2][r], s[3][r]));
            mx = fmaxf(mx, __shfl_xor(mx, 1, 64));
            mx = fmaxf(mx, __shfl_xor(mx, 2, 64));
            mx = fmaxf(mx, __shfl_xor(mx, 4, 64));
            mx = fmaxf(mx, __shfl_xor(mx, 8, 64));
            float mn = fmaxf(m[r], mx);
            float f  = __expf(m[r] - mn);   // first tile: exp(-inf)=0
            lsum[r] *= f;
            #pragma unroll
            for (int nt = 0; nt < 4; ++nt) o[nt][r] *= f;
            float su = 0.f;
            #pragma unroll
            for (int ct = 0; ct < 4; ++ct) {
                float p = __expf(s[ct][r] - mn);
                s[ct][r] = p;
                su += p;
            }
            su += __shfl_xor(su, 1, 64);
            su += __shfl_xor(su, 2, 64);
            su += __shfl_xor(su, 4, 64);
            su += __shfl_xor(su, 8, 64);
            lsum[r] += su;
            m[r] = mn;
        }

        // P -> per-wave LDS, hi/lo split, XOR-chunk swizzled for A-frag reads
        short* ph = &psh[w][0];
        short* pl = &psl[w][0];
        #pragma unroll
        for (int ct = 0; ct < 4; ++ct)
            #pragma unroll
            for (int r = 0; r < 4; ++r) {
                int qr    = hi4 * 4 + r;
                int chunk = (ct * 2 + (lo16 >> 3)) ^ (qr & 7);
                int idx   = qr * 64 + (chunk << 3) + (ln & 7);
                short hi, lo2;
                split_bf16(s[ct][r], hi, lo2);
                ph[idx] = hi;
                pl[idx] = lo2;
            }

        // P A-frags (within-wave LDS, compiler inserts lgkmcnt waits)
        bf16x8 pah[2], pal[2];
        #pragma unroll
        for (int kc = 0; kc < 2; ++kc) {
            int c   = (kc * 4 + hi4) ^ (lo16 & 7);
            int idx = lo16 * 64 + (c << 3);
            pah[kc] = *(const bf16x8*)(ph + idx);
            pal[kc] = *(const bf16x8*)(pl + idx);
        }

        // O += P V
        #pragma unroll
        for (int nt = 0; nt < 4; ++nt) {
            #pragma unroll
            for (int kc = 0; kc < 2; ++kc) {
                int row = nt * 16 + lo16;
                int c   = kc * 4 + hi4;
                int idx = row * 64 + ((c ^ (row & 7)) << 3);
                bf16x8 vbh = *(const bf16x8*)(vsh + idx);
                bf16x8 vbl = *(const bf16x8*)(vsl + idx);
                o[nt] = MFMA16(pah[kc], vbh, o[nt]);
                o[nt] = MFMA16(pah[kc], vbl, o[nt]);
                o[nt] = MFMA16(pal[kc], vbh, o[nt]);
            }
        }
    }

    // epilogue: normalize and store fp32 [b][l][h][d]
    const size_t obase = ((size_t)b * Ll) * Ee + (size_t)h * HD;
    #pragma unroll
    for (int r = 0; r < 4; ++r) {
        float inv = 1.0f / lsum[r];
        int qr = q0 + w * 16 + hi4 * 4 + r;
        #pragma unroll
        for (int nt = 0; nt < 4; ++nt)
            out[obase + (size_t)qr * Ee + nt * 16 + lo16] = o[nt][r] * inv;
    }
}

extern "C" void kernel_launch(void* const* d_in, const int* in_sizes, int n_in,
                              void* d_out, int out_size, void* d_ws, size_t ws_size,
                              hipStream_t stream) {
    const float* x  = (const float*)d_in[0];
    const float* Wq = (const float*)d_in[1];
    const float* bq = (const float*)d_in[2];
    const float* Wk = (const float*)d_in[3];
    const float* bk = (const float*)d_in[4];
    const float* Wv = (const float*)d_in[5];
    const float* bv = (const float*)d_in[6];
    float* outp = (float*)d_out;

    // Workspace: 6 bf16 arrays of B*L*E = 50.33 MB total (same as 3 fp32)
    const size_t ne = (size_t)Bb * Ll * Ee;
    short* Qhi  = (short*)d_ws;
    short* Qlo  = Qhi + ne;
    short* Khi  = Qlo + ne;
    short* Klo  = Khi + ne;
    short* Vthi = Klo + ne;
    short* Vtlo = Vthi + ne;

    dim3 gemm_grid(Ee / 64, (Bb * Ll) / 64, 3);   // (8, 128, 3)
    qkv_gemm_kernel<<<gemm_grid, 256, 0, stream>>>(x, Wq, bq, Wk, bk, Wv, bv,
                                                   Qhi, Qlo, Khi, Klo, Vthi, Vtlo);

    dim3 attn_grid(Ll / 64, NH, Bb);              // (32, 8, 4)
    attn_kernel<<<attn_grid, 256, 0, stream>>>(Qhi, Qlo, Khi, Klo, Vthi, Vtlo, outp);
}

// Round 10
// 359.963 us; speedup vs baseline: 2.6459x; 1.4349x over previous
//
#include <hip/hip_runtime.h>
#include <math.h>

// Problem constants
#define Bb 4
#define Ll 2048
#define Ee 512
#define NH 8
#define HD 64

typedef __attribute__((ext_vector_type(8))) short bf16x8;   // 8 bf16 = 4 VGPR
typedef __attribute__((ext_vector_type(4))) short bf16x4;   // 8 bytes
typedef __attribute__((ext_vector_type(4))) float f32x4;

#define MFMA16(a, b, c) __builtin_amdgcn_mfma_f32_16x16x32_bf16(a, b, c, 0, 0, 0)

// Split fp32 into bf16 hi + bf16 lo (RNE both). x ≈ hi + lo with ~2^-17 rel err.
__device__ inline void split_bf16(float x, short& hi, short& lo) {
    unsigned u = __float_as_uint(x);
    unsigned r = (u + 0x7fffu + ((u >> 16) & 1u)) & 0xffff0000u;
    hi = (short)(r >> 16);
    float rem = x - __uint_as_float(r);
    unsigned u2 = __float_as_uint(rem);
    unsigned r2 = u2 + 0x7fffu + ((u2 >> 16) & 1u);
    lo = (short)(r2 >> 16);
}

// ---------------------------------------------------------------------------
// split_x: x fp32 [M=8192][K=512] -> xsh/xsl bf16, k pre-swizzled per 64-group:
// chunk(8 elems) c -> c ^ (m&7). One thread = one chunk (8 elems, 16B stores).
// ---------------------------------------------------------------------------
__global__ __launch_bounds__(256) void split_x_kernel(
    const float* __restrict__ x, short* __restrict__ xsh, short* __restrict__ xsl)
{
    const size_t base = ((size_t)blockIdx.x * 256 + threadIdx.x) * 8;
    const int m = (int)(base >> 9);          // /512
    const int k = (int)(base & 511);
    const int c  = (k >> 3) & 7;
    const int g  = k & ~63;
    const int cs = c ^ (m & 7);
    float4 v0 = *(const float4*)(x + base);
    float4 v1 = *(const float4*)(x + base + 4);
    float f[8] = {v0.x, v0.y, v0.z, v0.w, v1.x, v1.y, v1.z, v1.w};
    bf16x8 hv, lv;
    #pragma unroll
    for (int i = 0; i < 8; ++i) {
        short th, tl;
        split_bf16(f[i], th, tl);
        hv[i] = th;
        lv[i] = tl;
    }
    const size_t dst = (size_t)m * 512 + g + (cs << 3);
    *(bf16x8*)(xsh + dst) = hv;
    *(bf16x8*)(xsl + dst) = lv;
}

// ---------------------------------------------------------------------------
// split_w: W fp32 [K=512][N=512] (z in {q,k,v}) -> wth/wtl bf16 TRANSPOSED
// [z][n=512][k=512], k pre-swizzled per 64-group: chunk c -> c ^ (n&7).
// 64x64 tiles via LDS transpose. Grid (8 k-tiles, 8 n-tiles, 3).
// ---------------------------------------------------------------------------
__global__ __launch_bounds__(256) void split_w_kernel(
    const float* __restrict__ Wq, const float* __restrict__ Wk,
    const float* __restrict__ Wv, short* __restrict__ wth, short* __restrict__ wtl)
{
    __shared__ float lds[64][65];
    const float* W = (blockIdx.z == 0) ? Wq : (blockIdx.z == 1) ? Wk : Wv;
    const int k0 = blockIdx.x * 64;
    const int n0 = blockIdx.y * 64;
    const int t  = threadIdx.x;

    #pragma unroll
    for (int it = 0; it < 16; ++it) {
        int lin = it * 256 + t;
        int kk = lin >> 6, nn = lin & 63;
        lds[kk][nn] = W[(size_t)(k0 + kk) * Ee + n0 + nn];
    }
    __syncthreads();

    #pragma unroll
    for (int it = 0; it < 2; ++it) {
        int task = it * 256 + t;          // 512 chunk-tasks: 64 n x 8 chunks
        int nn = task >> 3;
        int c  = task & 7;
        int n  = n0 + nn;
        int cs = c ^ (n & 7);
        bf16x8 hv, lv;
        #pragma unroll
        for (int i = 0; i < 8; ++i) {
            short th, tl;
            split_bf16(lds[c * 8 + i][nn], th, tl);
            hv[i] = th;
            lv[i] = tl;
        }
        size_t dst = (size_t)blockIdx.z * Ee * Ee + (size_t)n * 512 + k0 + (cs << 3);
        *(bf16x8*)(wth + dst) = hv;
        *(bf16x8*)(wtl + dst) = lv;
    }
}

// ---------------------------------------------------------------------------
// QKV projection via split-bf16 MFMA (3-product compensation ~ fp32).
// 64x64 C-tile, BK=64, 4 waves (wave w owns m-rows w*16..+16), 24 MFMA/wave/step.
// Same frag+swizzle conventions as attn_kernel (HW-validated round 9).
// Epilogue: D-frags -> padded LDS tile -> identical bias/split/layout writes.
// LDS: 4*8KB staging + 64*65*4 ost = 49.3 KB -> 3 blocks/CU.
// ---------------------------------------------------------------------------
__global__ __launch_bounds__(256) void qkv_mfma_kernel(
    const short* __restrict__ xsh, const short* __restrict__ xsl,
    const short* __restrict__ wth, const short* __restrict__ wtl,
    const float* __restrict__ bq, const float* __restrict__ bk,
    const float* __restrict__ bvec,
    short* __restrict__ Qhi, short* __restrict__ Qlo,
    short* __restrict__ Khi, short* __restrict__ Klo,
    short* __restrict__ Vthi, short* __restrict__ Vtlo)
{
    __shared__ short axh[4096], axl[4096], awh[4096], awl[4096];
    __shared__ float ost[64][65];

    const int t    = threadIdx.x;
    const int ln   = t & 63;
    const int w    = t >> 6;
    const int lo16 = ln & 15;
    const int hi4  = ln >> 4;
    const int n0 = blockIdx.x * 64;      // head h = blockIdx.x
    const int m0 = blockIdx.y * 64;
    const int z  = blockIdx.z;

    const float* bias = (z == 0) ? bq : (z == 1) ? bk : bvec;
    const short* wsh = wth + (size_t)z * Ee * Ee;
    const short* wsl = wtl + (size_t)z * Ee * Ee;

    f32x4 o[4];
    #pragma unroll
    for (int i = 0; i < 4; ++i) o[i] = (f32x4){0.f, 0.f, 0.f, 0.f};

    for (int k0 = 0; k0 < Ee; k0 += 64) {
        __syncthreads();
        // stage: wave 0->xh, 1->xl, 2->wh, 3->wl (each 64x64 bf16 = 8KB)
        const short* src;
        short* dst;
        if (w == 0)      { src = xsh + (size_t)m0 * 512 + k0; dst = axh; }
        else if (w == 1) { src = xsl + (size_t)m0 * 512 + k0; dst = axl; }
        else if (w == 2) { src = wsh + (size_t)n0 * 512 + k0; dst = awh; }
        else             { src = wsl + (size_t)n0 * 512 + k0; dst = awl; }
        #pragma unroll
        for (int it = 0; it < 8; ++it) {
            int row = it * 8 + (ln >> 3);
            *(bf16x8*)(dst + row * 64 + (ln & 7) * 8) =
                *(const bf16x8*)(src + (size_t)row * 512 + (ln & 7) * 8);
        }
        __syncthreads();

        #pragma unroll
        for (int kc = 0; kc < 2; ++kc) {
            int arow = w * 16 + lo16;
            int ac   = (kc * 4 + hi4) ^ (arow & 7);
            bf16x8 ah = *(const bf16x8*)(axh + arow * 64 + (ac << 3));
            bf16x8 al = *(const bf16x8*)(axl + arow * 64 + (ac << 3));
            #pragma unroll
            for (int nt = 0; nt < 4; ++nt) {
                int brow = nt * 16 + lo16;
                int bc   = (kc * 4 + hi4) ^ (brow & 7);
                bf16x8 bh = *(const bf16x8*)(awh + brow * 64 + (bc << 3));
                bf16x8 bl = *(const bf16x8*)(awl + brow * 64 + (bc << 3));
                o[nt] = MFMA16(ah, bh, o[nt]);
                o[nt] = MFMA16(ah, bl, o[nt]);
                o[nt] = MFMA16(al, bh, o[nt]);
            }
        }
    }

    // D-frags (col=lo16=n, row=hi4*4+r=m) -> LDS tile [m][n]
    #pragma unroll
    for (int nt = 0; nt < 4; ++nt)
        #pragma unroll
        for (int r = 0; r < 4; ++r)
            ost[w * 16 + hi4 * 4 + r][nt * 16 + lo16] = o[nt][r];
    __syncthreads();

    // phase 2: identical layout logic to the verified epilogue, reading ost
    const int tx = t & 15;
    const int ty = t >> 4;
    const int b  = m0 >> 11;
    const int l0 = m0 & 2047;
    const int h  = blockIdx.x;

    if (z < 2) {
        const float4 bv4 = *reinterpret_cast<const float4*>(&bias[n0 + tx * 4]);
        #pragma unroll
        for (int i = 0; i < 4; ++i) {
            int l = l0 + ty * 4 + i;
            size_t rowbase = ((size_t)(b * NH + h) * Ll + l) * (size_t)HD;
            float f[4];
            f[0] = ost[ty * 4 + i][tx * 4 + 0] + bv4.x;
            f[1] = ost[ty * 4 + i][tx * 4 + 1] + bv4.y;
            f[2] = ost[ty * 4 + i][tx * 4 + 2] + bv4.z;
            f[3] = ost[ty * 4 + i][tx * 4 + 3] + bv4.w;
            bf16x4 hv, lv;
            #pragma unroll
            for (int j = 0; j < 4; ++j) {
                short th, tl;
                split_bf16(f[j], th, tl);
                hv[j] = th;
                lv[j] = tl;
            }
            if (z == 0) {
                *(bf16x4*)(Qhi + rowbase + tx * 4) = hv;
                *(bf16x4*)(Qlo + rowbase + tx * 4) = lv;
            } else {
                int dpos = (((tx >> 1) ^ (l & 7)) << 3) + ((tx & 1) << 2);
                *(bf16x4*)(Khi + rowbase + dpos) = hv;
                *(bf16x4*)(Klo + rowbase + dpos) = lv;
            }
        }
    } else {
        #pragma unroll
        for (int it = 0; it < 16; ++it) {
            int lin = it * 256 + t;
            int d = lin >> 6, lloc = lin & 63;
            float f = ost[lloc][d] + bias[n0 + d];
            short hi, lo2;
            split_bf16(f, hi, lo2);
            int colp = ((((lloc >> 3) ^ (d & 7)) << 3) | (lloc & 7));
            size_t idx = ((size_t)(b * NH + h) * HD + d) * (size_t)Ll + l0 + colp;
            Vthi[idx] = hi;
            Vtlo[idx] = lo2;
        }
    }
}

// ---------------------------------------------------------------------------
// FALLBACK QKV projection (fp32 vector GEMM) — used only if ws_size is too
// small for the split arrays. Proven in round 9 (289 us).
// ---------------------------------------------------------------------------
__global__ __launch_bounds__(256) void qkv_gemm_kernel(
    const float* __restrict__ x,
    const float* __restrict__ Wq, const float* __restrict__ bq,
    const float* __restrict__ Wk, const float* __restrict__ bk,
    const float* __restrict__ Wv, const float* __restrict__ bv,
    short* __restrict__ Qhi, short* __restrict__ Qlo,
    short* __restrict__ Khi, short* __restrict__ Klo,
    short* __restrict__ Vthi, short* __restrict__ Vtlo)
{
    const float* W; const float* bias;
    if (blockIdx.z == 0)      { W = Wq; bias = bq; }
    else if (blockIdx.z == 1) { W = Wk; bias = bk; }
    else                      { W = Wv; bias = bv; }

    __shared__ float xs[16][65];
    __shared__ float ws[16][65];
    __shared__ float tr[64][65];

    const int t  = threadIdx.x;
    const int tx = t & 15;
    const int ty = t >> 4;
    const int m0 = blockIdx.y * 64;
    const int n0 = blockIdx.x * 64;
    const int h  = blockIdx.x;

    float acc[4][4] = {};

    for (int k0 = 0; k0 < Ee; k0 += 16) {
        __syncthreads();
        #pragma unroll
        for (int it = 0; it < 4; ++it) {
            int lin = it * 256 + t;
            int mm = lin >> 4, kk = lin & 15;
            xs[kk][mm] = x[(size_t)(m0 + mm) * Ee + (k0 + kk)];
            int kk2 = lin >> 6, c = lin & 63;
            ws[kk2][c] = W[(size_t)(k0 + kk2) * Ee + (n0 + c)];
        }
        __syncthreads();
        #pragma unroll
        for (int kk = 0; kk < 16; ++kk) {
            float a[4], b[4];
            #pragma unroll
            for (int i = 0; i < 4; ++i) a[i] = xs[kk][ty * 4 + i];
            #pragma unroll
            for (int j = 0; j < 4; ++j) b[j] = ws[kk][tx * 4 + j];
            #pragma unroll
            for (int i = 0; i < 4; ++i)
                #pragma unroll
                for (int j = 0; j < 4; ++j)
                    acc[i][j] = fmaf(a[i], b[j], acc[i][j]);
        }
    }

    const float4 bv4 = *reinterpret_cast<const float4*>(&bias[n0 + tx * 4]);
    const int z = blockIdx.z;
    const int b = m0 >> 11;
    const int l0 = m0 & 2047;

    if (z < 2) {
        #pragma unroll
        for (int i = 0; i < 4; ++i) {
            int l = l0 + ty * 4 + i;
            size_t rowbase = ((size_t)(b * NH + h) * Ll + l) * (size_t)HD;
            float f[4];
            f[0] = acc[i][0] + bv4.x;
            f[1] = acc[i][1] + bv4.y;
            f[2] = acc[i][2] + bv4.z;
            f[3] = acc[i][3] + bv4.w;
            bf16x4 hv, lv;
            #pragma unroll
            for (int j = 0; j < 4; ++j) {
                short th, tl;
                split_bf16(f[j], th, tl);
                hv[j] = th;
                lv[j] = tl;
            }
            if (z == 0) {
                *(bf16x4*)(Qhi + rowbase + tx * 4) = hv;
                *(bf16x4*)(Qlo + rowbase + tx * 4) = lv;
            } else {
                int dpos = (((tx >> 1) ^ (l & 7)) << 3) + ((tx & 1) << 2);
                *(bf16x4*)(Khi + rowbase + dpos) = hv;
                *(bf16x4*)(Klo + rowbase + dpos) = lv;
            }
        }
    } else {
        #pragma unroll
        for (int i = 0; i < 4; ++i) {
            tr[ty * 4 + i][tx * 4 + 0] = acc[i][0] + bv4.x;
            tr[ty * 4 + i][tx * 4 + 1] = acc[i][1] + bv4.y;
            tr[ty * 4 + i][tx * 4 + 2] = acc[i][2] + bv4.z;
            tr[ty * 4 + i][tx * 4 + 3] = acc[i][3] + bv4.w;
        }
        __syncthreads();
        #pragma unroll
        for (int it = 0; it < 16; ++it) {
            int lin = it * 256 + t;
            int d = lin >> 6, lloc = lin & 63;
            float f = tr[lloc][d];
            short hi, lo2;
            split_bf16(f, hi, lo2);
            int colp = ((((lloc >> 3) ^ (d & 7)) << 3) | (lloc & 7));
            size_t idx = ((size_t)(b * NH + h) * HD + d) * (size_t)Ll + l0 + colp;
            Vthi[idx] = hi;
            Vtlo[idx] = lo2;
        }
    }
}

// ---------------------------------------------------------------------------
// Flash attention, split-bf16 MFMA — UNCHANGED from round 9 (227 us, verified).
// ---------------------------------------------------------------------------
__global__ __launch_bounds__(256) void attn_kernel(
    const short* __restrict__ Qhi, const short* __restrict__ Qlo,
    const short* __restrict__ Khi, const short* __restrict__ Klo,
    const short* __restrict__ Vthi, const short* __restrict__ Vtlo,
    float* __restrict__ out)
{
    __shared__ short ksh[4096], ksl[4096], vsh[4096], vsl[4096];
    __shared__ short psh[4][1024], psl[4][1024];

    const int t    = threadIdx.x;
    const int ln   = t & 63;
    const int w    = t >> 6;
    const int lo16 = ln & 15;
    const int hi4  = ln >> 4;
    const int q0   = blockIdx.x * 64;
    const int h    = blockIdx.y;
    const int b    = blockIdx.z;
    const int bh   = b * NH + h;

    const size_t qbase = ((size_t)bh * Ll + q0 + w * 16 + lo16) * (size_t)HD;
    bf16x8 qh[2], ql[2];
    qh[0] = *(const bf16x8*)(Qhi + qbase + hi4 * 8);
    qh[1] = *(const bf16x8*)(Qhi + qbase + 32 + hi4 * 8);
    ql[0] = *(const bf16x8*)(Qlo + qbase + hi4 * 8);
    ql[1] = *(const bf16x8*)(Qlo + qbase + 32 + hi4 * 8);

    f32x4 o[4];
    float m[4], lsum[4];
    #pragma unroll
    for (int i = 0; i < 4; ++i) {
        o[i] = (f32x4){0.f, 0.f, 0.f, 0.f};
        m[i] = -INFINITY;
        lsum[i] = 0.f;
    }

    for (int kt = 0; kt < Ll; kt += 64) {
        __syncthreads();
        if (w < 2) {
            const short* src = (w == 0 ? Khi : Klo) + ((size_t)bh * Ll + kt) * (size_t)HD;
            short* dst = (w == 0 ? ksh : ksl);
            #pragma unroll
            for (int it = 0; it < 8; ++it)
                *(bf16x8*)(dst + it * 512 + ln * 8) = *(const bf16x8*)(src + it * 512 + ln * 8);
        } else {
            const short* src0 = (w == 2 ? Vthi : Vtlo) + (size_t)bh * HD * Ll + kt;
            short* dst = (w == 2 ? vsh : vsl);
            #pragma unroll
            for (int it = 0; it < 8; ++it) {
                int row = it * 8 + (ln >> 3);
                *(bf16x8*)(dst + row * 64 + (ln & 7) * 8) =
                    *(const bf16x8*)(src0 + (size_t)row * Ll + (ln & 7) * 8);
            }
        }
        __syncthreads();

        f32x4 s[4];
        #pragma unroll
        for (int ct = 0; ct < 4; ++ct) {
            s[ct] = (f32x4){0.f, 0.f, 0.f, 0.f};
            #pragma unroll
            for (int kc = 0; kc < 2; ++kc) {
                int key = ct * 16 + lo16;
                int c   = kc * 4 + hi4;
                int idx = key * 64 + ((c ^ (key & 7)) << 3);
                bf16x8 kbh = *(const bf16x8*)(ksh + idx);
                bf16x8 kbl = *(const bf16x8*)(ksl + idx);
                s[ct] = MFMA16(qh[kc], kbh, s[ct]);
                s[ct] = MFMA16(qh[kc], kbl, s[ct]);
                s[ct] = MFMA16(ql[kc], kbh, s[ct]);
            }
        }

        #pragma unroll
        for (int r = 0; r < 4; ++r) {
            float mx = fmaxf(fmaxf(s[0][r], s[1][r]), fmaxf(s[2][r], s[3][r]));
            mx = fmaxf(mx, __shfl_xor(mx, 1, 64));
            mx = fmaxf(mx, __shfl_xor(mx, 2, 64));
            mx = fmaxf(mx, __shfl_xor(mx, 4, 64));
            mx = fmaxf(mx, __shfl_xor(mx, 8, 64));
            float mn = fmaxf(m[r], mx);
            float f  = __expf(m[r] - mn);
            lsum[r] *= f;
            #pragma unroll
            for (int nt = 0; nt < 4; ++nt) o[nt][r] *= f;
            float su = 0.f;
            #pragma unroll
            for (int ct = 0; ct < 4; ++ct) {
                float p = __expf(s[ct][r] - mn);
                s[ct][r] = p;
                su += p;
            }
            su += __shfl_xor(su, 1, 64);
            su += __shfl_xor(su, 2, 64);
            su += __shfl_xor(su, 4, 64);
            su += __shfl_xor(su, 8, 64);
            lsum[r] += su;
            m[r] = mn;
        }

        short* ph = &psh[w][0];
        short* pl = &psl[w][0];
        #pragma unroll
        for (int ct = 0; ct < 4; ++ct)
            #pragma unroll
            for (int r = 0; r < 4; ++r) {
                int qr    = hi4 * 4 + r;
                int chunk = (ct * 2 + (lo16 >> 3)) ^ (qr & 7);
                int idx   = qr * 64 + (chunk << 3) + (ln & 7);
                short hi, lo2;
                split_bf16(s[ct][r], hi, lo2);
                ph[idx] = hi;
                pl[idx] = lo2;
            }

        bf16x8 pah[2], pal[2];
        #pragma unroll
        for (int kc = 0; kc < 2; ++kc) {
            int c   = (kc * 4 + hi4) ^ (lo16 & 7);
            int idx = lo16 * 64 + (c << 3);
            pah[kc] = *(const bf16x8*)(ph + idx);
            pal[kc] = *(const bf16x8*)(pl + idx);
        }

        #pragma unroll
        for (int nt = 0; nt < 4; ++nt) {
            #pragma unroll
            for (int kc = 0; kc < 2; ++kc) {
                int row = nt * 16 + lo16;
                int c   = kc * 4 + hi4;
                int idx = row * 64 + ((c ^ (row & 7)) << 3);
                bf16x8 vbh = *(const bf16x8*)(vsh + idx);
                bf16x8 vbl = *(const bf16x8*)(vsl + idx);
                o[nt] = MFMA16(pah[kc], vbh, o[nt]);
                o[nt] = MFMA16(pah[kc], vbl, o[nt]);
                o[nt] = MFMA16(pal[kc], vbh, o[nt]);
            }
        }
    }

    const size_t obase = ((size_t)b * Ll) * Ee + (size_t)h * HD;
    #pragma unroll
    for (int r = 0; r < 4; ++r) {
        float inv = 1.0f / lsum[r];
        int qr = q0 + w * 16 + hi4 * 4 + r;
        #pragma unroll
        for (int nt = 0; nt < 4; ++nt)
            out[obase + (size_t)qr * Ee + nt * 16 + lo16] = o[nt][r] * inv;
    }
}

extern "C" void kernel_launch(void* const* d_in, const int* in_sizes, int n_in,
                              void* d_out, int out_size, void* d_ws, size_t ws_size,
                              hipStream_t stream) {
    const float* x  = (const float*)d_in[0];
    const float* Wq = (const float*)d_in[1];
    const float* bq = (const float*)d_in[2];
    const float* Wk = (const float*)d_in[3];
    const float* bk = (const float*)d_in[4];
    const float* Wv = (const float*)d_in[5];
    const float* bv = (const float*)d_in[6];
    float* outp = (float*)d_out;

    // Workspace: Q..Vtlo (6*ne) + xsh/xsl (2*ne) + wth/wtl (2*3*E*E) shorts
    const size_t ne  = (size_t)Bb * Ll * Ee;   // 4194304
    const size_t wne = (size_t)3 * Ee * Ee;    // 786432
    short* Qhi  = (short*)d_ws;
    short* Qlo  = Qhi + ne;
    short* Khi  = Qlo + ne;
    short* Klo  = Khi + ne;
    short* Vthi = Klo + ne;
    short* Vtlo = Vthi + ne;
    short* xsh  = Vtlo + ne;
    short* xsl  = xsh + ne;
    short* wth  = xsl + ne;
    short* wtl  = wth + wne;
    const size_t needed = (8 * ne + 2 * wne) * sizeof(short);   // 70.25 MB

    dim3 gemm_grid(Ee / 64, (Bb * Ll) / 64, 3);   // (8, 128, 3)
    if (ws_size >= needed) {
        split_x_kernel<<<(int)(ne / 8 / 256), 256, 0, stream>>>(x, xsh, xsl);
        split_w_kernel<<<dim3(8, 8, 3), 256, 0, stream>>>(Wq, Wk, Wv, wth, wtl);
        qkv_mfma_kernel<<<gemm_grid, 256, 0, stream>>>(xsh, xsl, wth, wtl,
                                                       bq, bk, bv,
                                                       Qhi, Qlo, Khi, Klo, Vthi, Vtlo);
    } else {
        qkv_gemm_kernel<<<gemm_grid, 256, 0, stream>>>(x, Wq, bq, Wk, bk, Wv, bv,
                                                       Qhi, Qlo, Khi, Klo, Vthi, Vtlo);
    }

    dim3 attn_grid(Ll / 64, NH, Bb);              // (32, 8, 4)
    attn_kernel<<<attn_grid, 256, 0, stream>>>(Qhi, Qlo, Khi, Klo, Vthi, Vtlo, outp);
}

// Round 12
// 325.857 us; speedup vs baseline: 2.9228x; 1.1047x over previous
//
#include <hip/hip_runtime.h>
#include <math.h>

// Problem constants
#define Bb 4
#define Ll 2048
#define Ee 512
#define NH 8
#define HD 64

typedef __attribute__((ext_vector_type(8))) short bf16x8;   // 8 bf16 = 4 VGPR
typedef __attribute__((ext_vector_type(4))) short bf16x4;   // 8 bytes
typedef __attribute__((ext_vector_type(4))) float f32x4;

#define MFMA16(a, b, c) __builtin_amdgcn_mfma_f32_16x16x32_bf16(a, b, c, 0, 0, 0)

// Split fp32 into bf16 hi + bf16 lo (RNE both). x ≈ hi + lo with ~2^-17 rel err.
__device__ inline void split_bf16(float x, short& hi, short& lo) {
    unsigned u = __float_as_uint(x);
    unsigned r = (u + 0x7fffu + ((u >> 16) & 1u)) & 0xffff0000u;
    hi = (short)(r >> 16);
    float rem = x - __uint_as_float(r);
    unsigned u2 = __float_as_uint(rem);
    unsigned r2 = u2 + 0x7fffu + ((u2 >> 16) & 1u);
    lo = (short)(r2 >> 16);
}

// ---------------------------------------------------------------------------
// split_x: x fp32 [M=8192][K=512] -> xsh/xsl bf16, k pre-swizzled per 64-group
// ---------------------------------------------------------------------------
__global__ __launch_bounds__(256) void split_x_kernel(
    const float* __restrict__ x, short* __restrict__ xsh, short* __restrict__ xsl)
{
    const size_t base = ((size_t)blockIdx.x * 256 + threadIdx.x) * 8;
    const int m = (int)(base >> 9);
    const int k = (int)(base & 511);
    const int c  = (k >> 3) & 7;
    const int g  = k & ~63;
    const int cs = c ^ (m & 7);
    float4 v0 = *(const float4*)(x + base);
    float4 v1 = *(const float4*)(x + base + 4);
    float f[8] = {v0.x, v0.y, v0.z, v0.w, v1.x, v1.y, v1.z, v1.w};
    bf16x8 hv, lv;
    #pragma unroll
    for (int i = 0; i < 8; ++i) {
        short th, tl;
        split_bf16(f[i], th, tl);
        hv[i] = th;
        lv[i] = tl;
    }
    const size_t dst = (size_t)m * 512 + g + (cs << 3);
    *(bf16x8*)(xsh + dst) = hv;
    *(bf16x8*)(xsl + dst) = lv;
}

// ---------------------------------------------------------------------------
// split_w: W fp32 [K][N] (z in {q,k,v}) -> wth/wtl bf16 transposed [z][n][k],
// k pre-swizzled per 64-group: chunk c -> c ^ (n&7).
// ---------------------------------------------------------------------------
__global__ __launch_bounds__(256) void split_w_kernel(
    const float* __restrict__ Wq, const float* __restrict__ Wk,
    const float* __restrict__ Wv, short* __restrict__ wth, short* __restrict__ wtl)
{
    __shared__ float lds[64][65];
    const float* W = (blockIdx.z == 0) ? Wq : (blockIdx.z == 1) ? Wk : Wv;
    const int k0 = blockIdx.x * 64;
    const int n0 = blockIdx.y * 64;
    const int t  = threadIdx.x;

    #pragma unroll
    for (int it = 0; it < 16; ++it) {
        int lin = it * 256 + t;
        int kk = lin >> 6, nn = lin & 63;
        lds[kk][nn] = W[(size_t)(k0 + kk) * Ee + n0 + nn];
    }
    __syncthreads();

    #pragma unroll
    for (int it = 0; it < 2; ++it) {
        int task = it * 256 + t;
        int nn = task >> 3;
        int c  = task & 7;
        int n  = n0 + nn;
        int cs = c ^ (n & 7);
        bf16x8 hv, lv;
        #pragma unroll
        for (int i = 0; i < 8; ++i) {
            short th, tl;
            split_bf16(lds[c * 8 + i][nn], th, tl);
            hv[i] = th;
            lv[i] = tl;
        }
        size_t dst = (size_t)blockIdx.z * Ee * Ee + (size_t)n * 512 + k0 + (cs << 3);
        *(bf16x8*)(wth + dst) = hv;
        *(bf16x8*)(wtl + dst) = lv;
    }
}

// ---------------------------------------------------------------------------
// QKV projection via split-bf16 MFMA — UNCHANGED from round 10 (verified).
// ---------------------------------------------------------------------------
__global__ __launch_bounds__(256) void qkv_mfma_kernel(
    const short* __restrict__ xsh, const short* __restrict__ xsl,
    const short* __restrict__ wth, const short* __restrict__ wtl,
    const float* __restrict__ bq, const float* __restrict__ bk,
    const float* __restrict__ bvec,
    short* __restrict__ Qhi, short* __restrict__ Qlo,
    short* __restrict__ Khi, short* __restrict__ Klo,
    short* __restrict__ Vthi, short* __restrict__ Vtlo)
{
    __shared__ short axh[4096], axl[4096], awh[4096], awl[4096];
    __shared__ float ost[64][65];

    const int t    = threadIdx.x;
    const int ln   = t & 63;
    const int w    = t >> 6;
    const int lo16 = ln & 15;
    const int hi4  = ln >> 4;
    const int n0 = blockIdx.x * 64;
    const int m0 = blockIdx.y * 64;
    const int z  = blockIdx.z;

    const float* bias = (z == 0) ? bq : (z == 1) ? bk : bvec;
    const short* wsh = wth + (size_t)z * Ee * Ee;
    const short* wsl = wtl + (size_t)z * Ee * Ee;

    f32x4 o[4];
    #pragma unroll
    for (int i = 0; i < 4; ++i) o[i] = (f32x4){0.f, 0.f, 0.f, 0.f};

    for (int k0 = 0; k0 < Ee; k0 += 64) {
        __syncthreads();
        const short* src;
        short* dst;
        if (w == 0)      { src = xsh + (size_t)m0 * 512 + k0; dst = axh; }
        else if (w == 1) { src = xsl + (size_t)m0 * 512 + k0; dst = axl; }
        else if (w == 2) { src = wsh + (size_t)n0 * 512 + k0; dst = awh; }
        else             { src = wsl + (size_t)n0 * 512 + k0; dst = awl; }
        #pragma unroll
        for (int it = 0; it < 8; ++it) {
            int row = it * 8 + (ln >> 3);
            *(bf16x8*)(dst + row * 64 + (ln & 7) * 8) =
                *(const bf16x8*)(src + (size_t)row * 512 + (ln & 7) * 8);
        }
        __syncthreads();

        #pragma unroll
        for (int kc = 0; kc < 2; ++kc) {
            int arow = w * 16 + lo16;
            int ac   = (kc * 4 + hi4) ^ (arow & 7);
            bf16x8 ah = *(const bf16x8*)(axh + arow * 64 + (ac << 3));
            bf16x8 al = *(const bf16x8*)(axl + arow * 64 + (ac << 3));
            #pragma unroll
            for (int nt = 0; nt < 4; ++nt) {
                int brow = nt * 16 + lo16;
                int bc   = (kc * 4 + hi4) ^ (brow & 7);
                bf16x8 bh = *(const bf16x8*)(awh + brow * 64 + (bc << 3));
                bf16x8 bl = *(const bf16x8*)(awl + brow * 64 + (bc << 3));
                o[nt] = MFMA16(ah, bh, o[nt]);
                o[nt] = MFMA16(ah, bl, o[nt]);
                o[nt] = MFMA16(al, bh, o[nt]);
            }
        }
    }

    #pragma unroll
    for (int nt = 0; nt < 4; ++nt)
        #pragma unroll
        for (int r = 0; r < 4; ++r)
            ost[w * 16 + hi4 * 4 + r][nt * 16 + lo16] = o[nt][r];
    __syncthreads();

    const int tx = t & 15;
    const int ty = t >> 4;
    const int b  = m0 >> 11;
    const int l0 = m0 & 2047;
    const int h  = blockIdx.x;

    if (z < 2) {
        const float4 bv4 = *reinterpret_cast<const float4*>(&bias[n0 + tx * 4]);
        #pragma unroll
        for (int i = 0; i < 4; ++i) {
            int l = l0 + ty * 4 + i;
            size_t rowbase = ((size_t)(b * NH + h) * Ll + l) * (size_t)HD;
            float f[4];
            f[0] = ost[ty * 4 + i][tx * 4 + 0] + bv4.x;
            f[1] = ost[ty * 4 + i][tx * 4 + 1] + bv4.y;
            f[2] = ost[ty * 4 + i][tx * 4 + 2] + bv4.z;
            f[3] = ost[ty * 4 + i][tx * 4 + 3] + bv4.w;
            bf16x4 hv, lv;
            #pragma unroll
            for (int j = 0; j < 4; ++j) {
                short th, tl;
                split_bf16(f[j], th, tl);
                hv[j] = th;
                lv[j] = tl;
            }
            if (z == 0) {
                *(bf16x4*)(Qhi + rowbase + tx * 4) = hv;
                *(bf16x4*)(Qlo + rowbase + tx * 4) = lv;
            } else {
                int dpos = (((tx >> 1) ^ (l & 7)) << 3) + ((tx & 1) << 2);
                *(bf16x4*)(Khi + rowbase + dpos) = hv;
                *(bf16x4*)(Klo + rowbase + dpos) = lv;
            }
        }
    } else {
        #pragma unroll
        for (int it = 0; it < 16; ++it) {
            int lin = it * 256 + t;
            int d = lin >> 6, lloc = lin & 63;
            float f = ost[lloc][d] + bias[n0 + d];
            short hi, lo2;
            split_bf16(f, hi, lo2);
            int colp = ((((lloc >> 3) ^ (d & 7)) << 3) | (lloc & 7));
            size_t idx = ((size_t)(b * NH + h) * HD + d) * (size_t)Ll + l0 + colp;
            Vthi[idx] = hi;
            Vtlo[idx] = lo2;
        }
    }
}

// ---------------------------------------------------------------------------
// FALLBACK QKV (fp32 vector GEMM) — only if ws_size too small. Verified r9.
// ---------------------------------------------------------------------------
__global__ __launch_bounds__(256) void qkv_gemm_kernel(
    const float* __restrict__ x,
    const float* __restrict__ Wq, const float* __restrict__ bq,
    const float* __restrict__ Wk, const float* __restrict__ bk,
    const float* __restrict__ Wv, const float* __restrict__ bv,
    short* __restrict__ Qhi, short* __restrict__ Qlo,
    short* __restrict__ Khi, short* __restrict__ Klo,
    short* __restrict__ Vthi, short* __restrict__ Vtlo)
{
    const float* W; const float* bias;
    if (blockIdx.z == 0)      { W = Wq; bias = bq; }
    else if (blockIdx.z == 1) { W = Wk; bias = bk; }
    else                      { W = Wv; bias = bv; }

    __shared__ float xs[16][65];
    __shared__ float ws[16][65];
    __shared__ float tr[64][65];

    const int t  = threadIdx.x;
    const int tx = t & 15;
    const int ty = t >> 4;
    const int m0 = blockIdx.y * 64;
    const int n0 = blockIdx.x * 64;
    const int h  = blockIdx.x;

    float acc[4][4] = {};

    for (int k0 = 0; k0 < Ee; k0 += 16) {
        __syncthreads();
        #pragma unroll
        for (int it = 0; it < 4; ++it) {
            int lin = it * 256 + t;
            int mm = lin >> 4, kk = lin & 15;
            xs[kk][mm] = x[(size_t)(m0 + mm) * Ee + (k0 + kk)];
            int kk2 = lin >> 6, c = lin & 63;
            ws[kk2][c] = W[(size_t)(k0 + kk2) * Ee + (n0 + c)];
        }
        __syncthreads();
        #pragma unroll
        for (int kk = 0; kk < 16; ++kk) {
            float a[4], b[4];
            #pragma unroll
            for (int i = 0; i < 4; ++i) a[i] = xs[kk][ty * 4 + i];
            #pragma unroll
            for (int j = 0; j < 4; ++j) b[j] = ws[kk][tx * 4 + j];
            #pragma unroll
            for (int i = 0; i < 4; ++i)
                #pragma unroll
                for (int j = 0; j < 4; ++j)
                    acc[i][j] = fmaf(a[i], b[j], acc[i][j]);
        }
    }

    const float4 bv4 = *reinterpret_cast<const float4*>(&bias[n0 + tx * 4]);
    const int z = blockIdx.z;
    const int b = m0 >> 11;
    const int l0 = m0 & 2047;

    if (z < 2) {
        #pragma unroll
        for (int i = 0; i < 4; ++i) {
            int l = l0 + ty * 4 + i;
            size_t rowbase = ((size_t)(b * NH + h) * Ll + l) * (size_t)HD;
            float f[4];
            f[0] = acc[i][0] + bv4.x;
            f[1] = acc[i][1] + bv4.y;
            f[2] = acc[i][2] + bv4.z;
            f[3] = acc[i][3] + bv4.w;
            bf16x4 hv, lv;
            #pragma unroll
            for (int j = 0; j < 4; ++j) {
                short th, tl;
                split_bf16(f[j], th, tl);
                hv[j] = th;
                lv[j] = tl;
            }
            if (z == 0) {
                *(bf16x4*)(Qhi + rowbase + tx * 4) = hv;
                *(bf16x4*)(Qlo + rowbase + tx * 4) = lv;
            } else {
                int dpos = (((tx >> 1) ^ (l & 7)) << 3) + ((tx & 1) << 2);
                *(bf16x4*)(Khi + rowbase + dpos) = hv;
                *(bf16x4*)(Klo + rowbase + dpos) = lv;
            }
        }
    } else {
        #pragma unroll
        for (int i = 0; i < 4; ++i) {
            tr[ty * 4 + i][tx * 4 + 0] = acc[i][0] + bv4.x;
            tr[ty * 4 + i][tx * 4 + 1] = acc[i][1] + bv4.y;
            tr[ty * 4 + i][tx * 4 + 2] = acc[i][2] + bv4.z;
            tr[ty * 4 + i][tx * 4 + 3] = acc[i][3] + bv4.w;
        }
        __syncthreads();
        #pragma unroll
        for (int it = 0; it < 16; ++it) {
            int lin = it * 256 + t;
            int d = lin >> 6, lloc = lin & 63;
            float f = tr[lloc][d];
            short hi, lo2;
            split_bf16(f, hi, lo2);
            int colp = ((((lloc >> 3) ^ (d & 7)) << 3) | (lloc & 7));
            size_t idx = ((size_t)(b * NH + h) * HD + d) * (size_t)Ll + l0 + colp;
            Vthi[idx] = hi;
            Vtlo[idx] = lo2;
        }
    }
}

// ---------------------------------------------------------------------------
// Flash attention, split-bf16 MFMA, with T14 async-STAGE + double-buffered
// K/V LDS: loads for tile i+1 issue at top of iter i (hide under full compute),
// ds_writes to the alternate buffer land just before the single end barrier.
// Race-safety: iter i reads only buf[cur]; buf[cur^1]'s last readers finished
// before the barrier that ended iter i-1. K and V store layouts both
// linearize to it*512 + ln*8 (one store helper).
// LDS: 2*32KB (K/V hi/lo dbuf) + 16KB (P) = 80KB -> 2 blocks/CU (matches the
// 8 waves/CU already achieved at 48KB, so no occupancy loss).
// ---------------------------------------------------------------------------
__device__ inline void stage_ld(const short* __restrict__ Khi, const short* __restrict__ Klo,
                                const short* __restrict__ Vthi, const short* __restrict__ Vtlo,
                                int bh, int kt, int w, int ln, bf16x8* sr) {
    if (w < 2) {
        const short* src = (w == 0 ? Khi : Klo) + ((size_t)bh * Ll + kt) * (size_t)HD;
        #pragma unroll
        for (int it = 0; it < 8; ++it)
            sr[it] = *(const bf16x8*)(src + it * 512 + ln * 8);
    } else {
        const short* src0 = (w == 2 ? Vthi : Vtlo) + (size_t)bh * HD * Ll + kt;
        #pragma unroll
        for (int it = 0; it < 8; ++it) {
            int row = it * 8 + (ln >> 3);
            sr[it] = *(const bf16x8*)(src0 + (size_t)row * Ll + (ln & 7) * 8);
        }
    }
}

__global__ __launch_bounds__(256) void attn_kernel(
    const short* __restrict__ Qhi, const short* __restrict__ Qlo,
    const short* __restrict__ Khi, const short* __restrict__ Klo,
    const short* __restrict__ Vthi, const short* __restrict__ Vtlo,
    float* __restrict__ out)
{
    __shared__ short ksh[2][4096], ksl[2][4096], vsh[2][4096], vsl[2][4096];
    __shared__ short psh[4][1024], psl[4][1024];

    const int t    = threadIdx.x;
    const int ln   = t & 63;
    const int w    = t >> 6;
    const int lo16 = ln & 15;
    const int hi4  = ln >> 4;
    const int q0   = blockIdx.x * 64;
    const int h    = blockIdx.y;
    const int b    = blockIdx.z;
    const int bh   = b * NH + h;

    const size_t qbase = ((size_t)bh * Ll + q0 + w * 16 + lo16) * (size_t)HD;
    bf16x8 qh[2], ql[2];
    qh[0] = *(const bf16x8*)(Qhi + qbase + hi4 * 8);
    qh[1] = *(const bf16x8*)(Qhi + qbase + 32 + hi4 * 8);
    ql[0] = *(const bf16x8*)(Qlo + qbase + hi4 * 8);
    ql[1] = *(const bf16x8*)(Qlo + qbase + 32 + hi4 * 8);

    f32x4 o[4];
    float m[4], lsum[4];
    #pragma unroll
    for (int i = 0; i < 4; ++i) {
        o[i] = (f32x4){0.f, 0.f, 0.f, 0.f};
        m[i] = -INFINITY;
        lsum[i] = 0.f;
    }

    bf16x8 sr[8];

    // prologue: stage tile 0 into buffer 0
    stage_ld(Khi, Klo, Vthi, Vtlo, bh, 0, w, ln, sr);
    {
        short* dst = (w == 0) ? ksh[0] : (w == 1) ? ksl[0] : (w == 2) ? vsh[0] : vsl[0];
        #pragma unroll
        for (int it = 0; it < 8; ++it)
            *(bf16x8*)(dst + it * 512 + ln * 8) = sr[it];
    }
    __syncthreads();

    int cur = 0;
    for (int i = 0; i < Ll / 64; ++i) {
        // issue next tile's global loads (async; land during this iter's compute)
        if (i < Ll / 64 - 1)
            stage_ld(Khi, Klo, Vthi, Vtlo, bh, (i + 1) * 64, w, ln, sr);

        const short* kshc = ksh[cur];
        const short* kslc = ksl[cur];
        const short* vshc = vsh[cur];
        const short* vslc = vsl[cur];

        // S = Q K^T
        f32x4 s[4];
        #pragma unroll
        for (int ct = 0; ct < 4; ++ct) {
            s[ct] = (f32x4){0.f, 0.f, 0.f, 0.f};
            #pragma unroll
            for (int kc = 0; kc < 2; ++kc) {
                int key = ct * 16 + lo16;
                int c   = kc * 4 + hi4;
                int idx = key * 64 + ((c ^ (key & 7)) << 3);
                bf16x8 kbh = *(const bf16x8*)(kshc + idx);
                bf16x8 kbl = *(const bf16x8*)(kslc + idx);
                s[ct] = MFMA16(qh[kc], kbh, s[ct]);
                s[ct] = MFMA16(qh[kc], kbl, s[ct]);
                s[ct] = MFMA16(ql[kc], kbh, s[ct]);
            }
        }

        // online softmax per q-row
        #pragma unroll
        for (int r = 0; r < 4; ++r) {
            float mx = fmaxf(fmaxf(s[0][r], s[1][r]), fmaxf(s[2][r], s[3][r]));
            mx = fmaxf(mx, __shfl_xor(mx, 1, 64));
            mx = fmaxf(mx, __shfl_xor(mx, 2, 64));
            mx = fmaxf(mx, __shfl_xor(mx, 4, 64));
            mx = fmaxf(mx, __shfl_xor(mx, 8, 64));
            float mn = fmaxf(m[r], mx);
            float f  = __expf(m[r] - mn);
            lsum[r] *= f;
            #pragma unroll
            for (int nt = 0; nt < 4; ++nt) o[nt][r] *= f;
            float su = 0.f;
            #pragma unroll
            for (int ct = 0; ct < 4; ++ct) {
                float p = __expf(s[ct][r] - mn);
                s[ct][r] = p;
                su += p;
            }
            su += __shfl_xor(su, 1, 64);
            su += __shfl_xor(su, 2, 64);
            su += __shfl_xor(su, 4, 64);
            su += __shfl_xor(su, 8, 64);
            lsum[r] += su;
            m[r] = mn;
        }

        // P -> per-wave LDS (hi/lo, swizzled), then A-frags
        short* ph = &psh[w][0];
        short* pl = &psl[w][0];
        #pragma unroll
        for (int ct = 0; ct < 4; ++ct)
            #pragma unroll
            for (int r = 0; r < 4; ++r) {
                int qr    = hi4 * 4 + r;
                int chunk = (ct * 2 + (lo16 >> 3)) ^ (qr & 7);
                int idx   = qr * 64 + (chunk << 3) + (ln & 7);
                short hi, lo2;
                split_bf16(s[ct][r], hi, lo2);
                ph[idx] = hi;
                pl[idx] = lo2;
            }

        bf16x8 pah[2], pal[2];
        #pragma unroll
        for (int kc = 0; kc < 2; ++kc) {
            int c   = (kc * 4 + hi4) ^ (lo16 & 7);
            int idx = lo16 * 64 + (c << 3);
            pah[kc] = *(const bf16x8*)(ph + idx);
            pal[kc] = *(const bf16x8*)(pl + idx);
        }

        // O += P V
        #pragma unroll
        for (int nt = 0; nt < 4; ++nt) {
            #pragma unroll
            for (int kc = 0; kc < 2; ++kc) {
                int row = nt * 16 + lo16;
                int c   = kc * 4 + hi4;
                int idx = row * 64 + ((c ^ (row & 7)) << 3);
                bf16x8 vbh = *(const bf16x8*)(vshc + idx);
                bf16x8 vbl = *(const bf16x8*)(vslc + idx);
                o[nt] = MFMA16(pah[kc], vbh, o[nt]);
                o[nt] = MFMA16(pah[kc], vbl, o[nt]);
                o[nt] = MFMA16(pal[kc], vbh, o[nt]);
            }
        }

        // write next tile into the alternate buffer (vmcnt waits attach here;
        // buf[cur^1] is free — its readers finished before last iter's barrier)
        if (i < Ll / 64 - 1) {
            short* dst = (w == 0) ? ksh[cur ^ 1] : (w == 1) ? ksl[cur ^ 1]
                       : (w == 2) ? vsh[cur ^ 1] : vsl[cur ^ 1];
            #pragma unroll
            for (int it = 0; it < 8; ++it)
                *(bf16x8*)(dst + it * 512 + ln * 8) = sr[it];
        }
        __syncthreads();   // single barrier: reads of buf[cur] done, writes visible
        cur ^= 1;
    }

    const size_t obase = ((size_t)b * Ll) * Ee + (size_t)h * HD;
    #pragma unroll
    for (int r = 0; r < 4; ++r) {
        float inv = 1.0f / lsum[r];
        int qr = q0 + w * 16 + hi4 * 4 + r;
        #pragma unroll
        for (int nt = 0; nt < 4; ++nt)
            out[obase + (size_t)qr * Ee + nt * 16 + lo16] = o[nt][r] * inv;
    }
}

extern "C" void kernel_launch(void* const* d_in, const int* in_sizes, int n_in,
                              void* d_out, int out_size, void* d_ws, size_t ws_size,
                              hipStream_t stream) {
    const float* x  = (const float*)d_in[0];
    const float* Wq = (const float*)d_in[1];
    const float* bq = (const float*)d_in[2];
    const float* Wk = (const float*)d_in[3];
    const float* bk = (const float*)d_in[4];
    const float* Wv = (const float*)d_in[5];
    const float* bv = (const float*)d_in[6];
    float* outp = (float*)d_out;

    const size_t ne  = (size_t)Bb * Ll * Ee;   // 4194304
    const size_t wne = (size_t)3 * Ee * Ee;    // 786432
    short* Qhi  = (short*)d_ws;
    short* Qlo  = Qhi + ne;
    short* Khi  = Qlo + ne;
    short* Klo  = Khi + ne;
    short* Vthi = Klo + ne;
    short* Vtlo = Vthi + ne;
    short* xsh  = Vtlo + ne;
    short* xsl  = xsh + ne;
    short* wth  = xsl + ne;
    short* wtl  = wth + wne;
    const size_t needed = (8 * ne + 2 * wne) * sizeof(short);   // 70.25 MB

    dim3 gemm_grid(Ee / 64, (Bb * Ll) / 64, 3);   // (8, 128, 3)
    if (ws_size >= needed) {
        split_x_kernel<<<(int)(ne / 8 / 256), 256, 0, stream>>>(x, xsh, xsl);
        split_w_kernel<<<dim3(8, 8, 3), 256, 0, stream>>>(Wq, Wk, Wv, wth, wtl);
        qkv_mfma_kernel<<<gemm_grid, 256, 0, stream>>>(xsh, xsl, wth, wtl,
                                                       bq, bk, bv,
                                                       Qhi, Qlo, Khi, Klo, Vthi, Vtlo);
    } else {
        qkv_gemm_kernel<<<gemm_grid, 256, 0, stream>>>(x, Wq, bq, Wk, bk, Wv, bv,
                                                       Qhi, Qlo, Khi, Klo, Vthi, Vtlo);
    }

    dim3 attn_grid(Ll / 64, NH, Bb);              // (32, 8, 4)
    attn_kernel<<<attn_grid, 256, 0, stream>>>(Qhi, Qlo, Khi, Klo, Vthi, Vtlo, outp);
}